// Round 9
// baseline (587.999 us; speedup 1.0000x reference)
//
#include <hip/hip_runtime.h>
#include <hip/hip_bf16.h>
#include <cstddef>
#include <cstdint>

#define N_NODES 50000
#define N_EDGES 800000
#define IN_CH 128
#define HID 64
#define OUT_CH 32

#define NBUCK 782    // buckets of 64 dst nodes (ceil(50000/64))
#define NBLK 256     // partition blocks
#define EPB 3125     // edges per partition block (256*3125 = 800000 exactly)

typedef __attribute__((ext_vector_type(8))) short bf16x8;
typedef __attribute__((ext_vector_type(4))) float f32x4;

// bf16 round-to-nearest-even, bit form
__device__ __forceinline__ unsigned short bf16rne(float f) {
    union { float f; unsigned u; } c; c.f = f;
    unsigned r = c.u + 0x7FFF + ((c.u >> 16) & 1);
    return (unsigned short)(r >> 16);
}
__device__ __forceinline__ float bf16f(unsigned short b) {
    union { unsigned u; float f; } c; c.u = ((unsigned)b) << 16;
    return c.f;
}

// ---------------- edge decode (int32 vs int64 decided at runtime) ----------
__device__ __forceinline__ void load_edge(const void* ei, int flag, int e, int& s, int& d) {
    if (flag) {  // int64 data
        const long long* p = (const long long*)ei;
        s = (int)p[e];
        d = (int)p[e + N_EDGES];
    } else {     // int32 data
        const int* p = (const int*)ei;
        s = p[e];
        d = p[e + N_EDGES];
    }
}
__device__ __forceinline__ int load_dst(const void* ei, int flag, int e) {
    return flag ? (int)((const long long*)ei)[e + N_EDGES]
                : ((const int*)ei)[e + N_EDGES];
}

// flag=1 iff data is int64: odd int32 words (high halves) are all zero.
__global__ __launch_bounds__(256) void detect_kernel(const unsigned* ei, int* flagp) {
    __shared__ unsigned red[256];
    unsigned acc = 0;
    for (int i = threadIdx.x; i < 2048; i += 256) acc |= ei[2 * i + 1];
    red[threadIdx.x] = acc;
    __syncthreads();
    if (threadIdx.x == 0) {
        unsigned o = 0;
        for (int i = 0; i < 256; ++i) o |= red[i];
        *flagp = (o == 0) ? 1 : 0;
    }
}

// ---- pass A: per-block bucket histogram; also bucket totals via atomics ---
// ghistT layout: [bucket][block]
__global__ __launch_bounds__(256) void hist_kernel(const void* ei, const int* flagp,
                                                   int* __restrict__ ghistT,
                                                   int* __restrict__ btotal) {
    __shared__ int h[NBUCK];
    const int flag = *flagp;
    const int t = threadIdx.x;
    for (int u = t; u < NBUCK; u += 256) h[u] = 0;
    __syncthreads();
    const int base = blockIdx.x * EPB;
    for (int i = t; i < EPB; i += 256)
        atomicAdd(&h[load_dst(ei, flag, base + i) >> 6], 1);
    __syncthreads();
    for (int u = t; u < NBUCK; u += 256) {
        ghistT[u * NBLK + blockIdx.x] = h[u];
        if (h[u]) atomicAdd(&btotal[u], h[u]);
    }
}

// ---- pass B1: exclusive scan of 782 bucket totals (1 block, 1024 thr) -----
__global__ __launch_bounds__(1024) void btot_kernel(const int* __restrict__ btotal,
                                                    int* __restrict__ bstart) {
    __shared__ int sm[1024];
    const int t = threadIdx.x;
    int v = (t < NBUCK) ? btotal[t] : 0;
    sm[t] = v;
    __syncthreads();
    for (int off = 1; off < 1024; off <<= 1) {
        int u = (t >= off) ? sm[t - off] : 0;
        __syncthreads();
        sm[t] += u;
        __syncthreads();
    }
    if (t < NBUCK) bstart[t] = sm[t] - v;
    if (t == 1023) bstart[NBUCK] = sm[1023];
}

// ---- pass B2: per-bucket scan over the 256 block counts -> goff[blk][b] ---
__global__ __launch_bounds__(256) void offs_kernel(const int* __restrict__ bstart,
                                                   const int* __restrict__ ghistT,
                                                   int* __restrict__ goff) {
    __shared__ int sm[256];
    const int b = blockIdx.x;
    const int t = threadIdx.x;
    int v = ghistT[b * NBLK + t];
    sm[t] = v;
    __syncthreads();
    for (int off = 1; off < 256; off <<= 1) {
        int u = (t >= off) ? sm[t - off] : 0;
        __syncthreads();
        sm[t] += u;
        __syncthreads();
    }
    goff[t * NBUCK + b] = bstart[b] + sm[t] - v;  // exclusive prefix
}

// ---- pass C: scatter into disjoint per-(block,bucket) ranges --------------
// packed: src (16b) | dlocal (6b at bit 16)
__global__ __launch_bounds__(256) void scatter_kernel(const void* ei, const int* flagp,
                                                      const int* __restrict__ goff,
                                                      unsigned* __restrict__ packed) {
    __shared__ int lcur[NBUCK];
    const int flag = *flagp;
    const int t = threadIdx.x;
    for (int u = t; u < NBUCK; u += 256) lcur[u] = goff[blockIdx.x * NBUCK + u];
    __syncthreads();
    const int base = blockIdx.x * EPB;
    for (int i = t; i < EPB; i += 256) {
        int s, d;
        load_edge(ei, flag, base + i, s, d);
        int b = d >> 6;
        int pos = atomicAdd(&lcur[b], 1);
        packed[pos] = (unsigned)s | ((unsigned)(d & 63) << 16);
    }
}

// ---- pass D: per-bucket degree histogram -> dis ---------------------------
__global__ __launch_bounds__(256) void dispass_kernel(const int* __restrict__ bstart,
                                                      const unsigned* __restrict__ packed,
                                                      float* __restrict__ dis) {
    __shared__ int cnt[64];
    const int b = blockIdx.x;
    const int t = threadIdx.x;
    if (t < 64) cnt[t] = 0;
    __syncthreads();
    const int rbeg = bstart[b], rend = bstart[b + 1];
    for (int i = rbeg + t; i < rend; i += 256)
        atomicAdd(&cnt[(packed[i] >> 16) & 63], 1);
    __syncthreads();
    if (t < 64) {
        int node = (b << 6) + t;
        if (node < N_NODES) dis[node] = rsqrtf((float)cnt[t] + 1.0f);
    }
}

// --------------- GEMM1 (MFMA bf16): h1b = bf16(x @ W1) ---------------------
// block: 64 rows x 64 cols, K=128; 4 waves, each wave 16 rows x 64 cols.
__global__ __launch_bounds__(256) void gemm1_kernel(
        const float* __restrict__ x, const float* __restrict__ W1,
        unsigned short* __restrict__ h1b) {
    __shared__ unsigned short xa[64][136];  // x tile, bf16, +8 pad
    __shared__ unsigned short wb[64][136];  // W1 transposed [n][k], bf16
    const int t = threadIdx.x;
    const int w = t >> 6;
    const int l = t & 63;
    const int brow = blockIdx.x * 64;

    for (int f = t; f < 64 * 32; f += 256) {
        int r = f >> 5, c = (f & 31) << 2;
        int gr = brow + r;
        float4 v = (gr < N_NODES) ? *(const float4*)(x + gr * IN_CH + c)
                                  : make_float4(0.f, 0.f, 0.f, 0.f);
        xa[r][c + 0] = bf16rne(v.x); xa[r][c + 1] = bf16rne(v.y);
        xa[r][c + 2] = bf16rne(v.z); xa[r][c + 3] = bf16rne(v.w);
    }
    for (int f = t; f < 128 * 16; f += 256) {
        int k = f >> 4, n = (f & 15) << 2;
        float4 v = *(const float4*)(W1 + k * HID + n);
        wb[n + 0][k] = bf16rne(v.x); wb[n + 1][k] = bf16rne(v.y);
        wb[n + 2][k] = bf16rne(v.z); wb[n + 3][k] = bf16rne(v.w);
    }
    __syncthreads();

    const int fr = l & 15;
    const int fk = (l >> 4) << 3;
    f32x4 acc[4] = {{0.f,0.f,0.f,0.f},{0.f,0.f,0.f,0.f},{0.f,0.f,0.f,0.f},{0.f,0.f,0.f,0.f}};
#pragma unroll
    for (int kb = 0; kb < 4; ++kb) {
        const int k = kb * 32 + fk;
        bf16x8 a = *(const bf16x8*)&xa[w * 16 + fr][k];
#pragma unroll
        for (int n = 0; n < 4; ++n) {
            bf16x8 bfr = *(const bf16x8*)&wb[n * 16 + fr][k];
            acc[n] = __builtin_amdgcn_mfma_f32_16x16x32_bf16(a, bfr, acc[n], 0, 0, 0);
        }
    }
    const int rb = brow + w * 16 + ((l >> 4) << 2);
#pragma unroll
    for (int n = 0; n < 4; ++n) {
#pragma unroll
        for (int i = 0; i < 4; ++i) {
            int r = rb + i;
            if (r < N_NODES) h1b[r * HID + n * 16 + fr] = bf16rne(acc[n][i]);
        }
    }
}

// ---- fused agg1 + gemm2: per bucket of 64 dsts ----------------------------
// acc[dl][c] += h1[src][c]*norm  (LDS f32 atomics, streaming packed edges)
// then relu(acc + self + b1) -> bf16 xa -> MFMA with W2 -> h2b
__global__ __launch_bounds__(256) void agg1gemm2_kernel(
        const int* __restrict__ bstart, const unsigned* __restrict__ packed,
        const float* __restrict__ dis, const unsigned short* __restrict__ h1b,
        const float* __restrict__ b1, const float* __restrict__ W2,
        unsigned short* __restrict__ h2b) {
    __shared__ float acc[64][64];          // 16 KB
    __shared__ unsigned short xa[64][72];  // 9 KB (+8 pad)
    __shared__ unsigned short wb[32][72];  // 4.5 KB
    __shared__ float disl[64];
    const int t = threadIdx.x;
    const int w = t >> 6;
    const int lane = t & 63;
    const int b = blockIdx.x;
    const int base = b << 6;

    // init acc, disl; stage W2 transposed bf16
    for (int f = t; f < 64 * 16; f += 256) *(float4*)&acc[f >> 4][(f & 15) << 2] =
        make_float4(0.f, 0.f, 0.f, 0.f);
    if (t < 64) {
        int node = base + t;
        disl[t] = (node < N_NODES) ? dis[node] : 0.f;
    }
    for (int f = t; f < 64 * 8; f += 256) {
        int k = f >> 3, n = (f & 7) << 2;
        float4 v = *(const float4*)(W2 + k * OUT_CH + n);
        wb[n + 0][k] = bf16rne(v.x); wb[n + 1][k] = bf16rne(v.y);
        wb[n + 2][k] = bf16rne(v.z); wb[n + 3][k] = bf16rne(v.w);
    }
    __syncthreads();

    // stream edges: wave w takes j = rbeg + w (mod 4), unroll 2
    const int rbeg = bstart[b], rend = bstart[b + 1];
    int j = rbeg + w;
    for (; j + 4 < rend; j += 8) {
        unsigned p0 = packed[j], p1 = packed[j + 4];
        int s0 = p0 & 0xFFFFu, dl0 = (p0 >> 16) & 63;
        int s1 = p1 & 0xFFFFu, dl1 = (p1 >> 16) & 63;
        float n0 = dis[s0] * disl[dl0];
        float n1 = dis[s1] * disl[dl1];
        float h0 = bf16f(h1b[s0 * HID + lane]);
        float h1v = bf16f(h1b[s1 * HID + lane]);
        atomicAdd(&acc[dl0][lane], h0 * n0);
        atomicAdd(&acc[dl1][lane], h1v * n1);
    }
    if (j < rend) {
        unsigned p0 = packed[j];
        int s0 = p0 & 0xFFFFu, dl0 = (p0 >> 16) & 63;
        float n0 = dis[s0] * disl[dl0];
        atomicAdd(&acc[dl0][lane], bf16f(h1b[s0 * HID + lane]) * n0);
    }
    __syncthreads();

    // epilogue: self-loop + bias + relu -> bf16 xa
    {
        const float bv = b1[lane];
        const int rg = (t >> 6) << 4;  // 16 rows per wave
        for (int i = 0; i < 16; ++i) {
            int r = rg + i;
            int node = base + r;
            float v = 0.f;
            if (node < N_NODES) {
                float dd = disl[r];
                v = acc[r][lane] + bf16f(h1b[node * HID + lane]) * (dd * dd) + bv;
                v = fmaxf(v, 0.f);
            }
            xa[r][lane] = bf16rne(v);
        }
    }
    __syncthreads();

    // gemm2 MFMA: 4 waves x 16 rows x 32 cols, K=64
    const int fr = lane & 15;
    const int fk = (lane >> 4) << 3;
    f32x4 c2[2] = {{0.f,0.f,0.f,0.f},{0.f,0.f,0.f,0.f}};
#pragma unroll
    for (int kb = 0; kb < 2; ++kb) {
        const int k = kb * 32 + fk;
        bf16x8 a = *(const bf16x8*)&xa[w * 16 + fr][k];
#pragma unroll
        for (int n = 0; n < 2; ++n) {
            bf16x8 bfr = *(const bf16x8*)&wb[n * 16 + fr][k];
            c2[n] = __builtin_amdgcn_mfma_f32_16x16x32_bf16(a, bfr, c2[n], 0, 0, 0);
        }
    }
    const int rb = base + w * 16 + ((lane >> 4) << 2);
#pragma unroll
    for (int n = 0; n < 2; ++n) {
#pragma unroll
        for (int i = 0; i < 4; ++i) {
            int r = rb + i;
            if (r < N_NODES) h2b[r * OUT_CH + n * 16 + fr] = bf16rne(c2[n][i]);
        }
    }
}

// ---- fused agg2: per bucket of 64 dsts, LDS accumulate, write out ---------
__global__ __launch_bounds__(256) void agg2_kernel(
        const int* __restrict__ bstart, const unsigned* __restrict__ packed,
        const float* __restrict__ dis, const unsigned short* __restrict__ h2b,
        const float* __restrict__ b2, float* __restrict__ out) {
    __shared__ float acc[64][32];  // 8 KB
    __shared__ float disl[64];
    const int t = threadIdx.x;
    const int w = t >> 6;
    const int lane = t & 63;
    const int half = lane >> 5;
    const int c = lane & 31;
    const int b = blockIdx.x;
    const int base = b << 6;

    for (int f = t; f < 64 * 8; f += 256) *(float4*)&acc[f >> 3][(f & 7) << 2] =
        make_float4(0.f, 0.f, 0.f, 0.f);
    if (t < 64) {
        int node = base + t;
        disl[t] = (node < N_NODES) ? dis[node] : 0.f;
    }
    __syncthreads();

    // 2 edges per wave-iter (half-waves), unroll 2 -> stride 16
    const int rbeg = bstart[b], rend = bstart[b + 1];
    int j = rbeg + w * 2 + half;
    for (; j + 8 < rend; j += 16) {
        unsigned p0 = packed[j], p1 = packed[j + 8];
        int s0 = p0 & 0xFFFFu, dl0 = (p0 >> 16) & 63;
        int s1 = p1 & 0xFFFFu, dl1 = (p1 >> 16) & 63;
        float n0 = dis[s0] * disl[dl0];
        float n1 = dis[s1] * disl[dl1];
        float h0 = bf16f(h2b[s0 * OUT_CH + c]);
        float h1v = bf16f(h2b[s1 * OUT_CH + c]);
        atomicAdd(&acc[dl0][c], h0 * n0);
        atomicAdd(&acc[dl1][c], h1v * n1);
    }
    if (j < rend) {
        unsigned p0 = packed[j];
        int s0 = p0 & 0xFFFFu, dl0 = (p0 >> 16) & 63;
        float n0 = dis[s0] * disl[dl0];
        atomicAdd(&acc[dl0][c], bf16f(h2b[s0 * OUT_CH + c]) * n0);
    }
    __syncthreads();

    // epilogue: out = acc + self + b2
    {
        const int c2 = t & 31;
        const float bv = b2[c2];
        const int rg = (t >> 5) << 3;  // 8 rows per 32-thread group
        for (int i = 0; i < 8; ++i) {
            int r = rg + i;
            int node = base + r;
            if (node < N_NODES) {
                float dd = disl[r];
                out[node * OUT_CH + c2] =
                    acc[r][c2] + bf16f(h2b[node * OUT_CH + c2]) * (dd * dd) + bv;
            }
        }
    }
}

extern "C" void kernel_launch(void* const* d_in, const int* in_sizes, int n_in,
                              void* d_out, int out_size, void* d_ws, size_t ws_size,
                              hipStream_t stream) {
    const float* x  = (const float*)d_in[0];
    const float* W1 = (const float*)d_in[1];
    const float* b1 = (const float*)d_in[2];
    const float* W2 = (const float*)d_in[3];
    const float* b2 = (const float*)d_in[4];
    const void*  ei = d_in[5];
    float* out = (float*)d_out;

    char* wp = (char*)d_ws;
    auto alloc = [&](size_t n) { char* p = wp; wp += (n + 511) & ~(size_t)511; return p; };
    int*   flagp  = (int*)alloc(4);
    int*   btotal = (int*)alloc(NBUCK * 4);
    int*   bstart = (int*)alloc((NBUCK + 1) * 4);
    int*   ghistT = (int*)alloc((size_t)NBUCK * NBLK * 4);   // 800 KB
    int*   goff   = (int*)alloc((size_t)NBLK * NBUCK * 4);   // 800 KB
    float* dis    = (float*)alloc(N_NODES * 4);              // 200 KB
    unsigned* packed = (unsigned*)alloc((size_t)N_EDGES * 4);            // 3.2 MB
    unsigned short* h1b = (unsigned short*)alloc((size_t)N_NODES * HID * 2);   // 6.4 MB
    unsigned short* h2b = (unsigned short*)alloc((size_t)N_NODES * OUT_CH * 2); // 3.2 MB

    hipMemsetAsync(btotal, 0, NBUCK * sizeof(int), stream);
    detect_kernel<<<1, 256, 0, stream>>>((const unsigned*)ei, flagp);
    hist_kernel<<<NBLK, 256, 0, stream>>>(ei, flagp, ghistT, btotal);
    btot_kernel<<<1, 1024, 0, stream>>>(btotal, bstart);
    offs_kernel<<<NBUCK, 256, 0, stream>>>(bstart, ghistT, goff);
    scatter_kernel<<<NBLK, 256, 0, stream>>>(ei, flagp, goff, packed);
    dispass_kernel<<<NBUCK, 256, 0, stream>>>(bstart, packed, dis);

    gemm1_kernel<<<(N_NODES + 63) / 64, 256, 0, stream>>>(x, W1, h1b);

    agg1gemm2_kernel<<<NBUCK, 256, 0, stream>>>(bstart, packed, dis, h1b, b1, W2, h2b);

    agg2_kernel<<<NBUCK, 256, 0, stream>>>(bstart, packed, dis, h2b, b2, out);
}

// Round 10
// 109.047 us; speedup vs baseline: 5.3922x; 5.3922x over previous
//
#include <hip/hip_runtime.h>
#include <hip/hip_bf16.h>
#include <cstddef>
#include <cstdint>

#define N_NODES 50000
#define N_EDGES 800000
#define IN_CH 128
#define HID 64
#define OUT_CH 32

#define NBUCK 196    // buckets of 256 dst nodes
#define BCAP 8192    // LDS bucket capacity (mean 4082, sigma ~64)
#define NBLK 256     // partition blocks
#define EPB 3125     // edges per partition block (256*3125 = 800000 exactly)

typedef __attribute__((ext_vector_type(8))) short bf16x8;
typedef __attribute__((ext_vector_type(8))) unsigned short u16x8;
typedef __attribute__((ext_vector_type(4))) float f32x4;

// bf16 round-to-nearest-even, bit form
__device__ __forceinline__ unsigned short bf16rne(float f) {
    union { float f; unsigned u; } c; c.f = f;
    unsigned r = c.u + 0x7FFF + ((c.u >> 16) & 1);
    return (unsigned short)(r >> 16);
}
__device__ __forceinline__ float bf16f(unsigned short b) {
    union { unsigned u; float f; } c; c.u = ((unsigned)b) << 16;
    return c.f;
}

// ---------------- edge decode (int32 vs int64 decided at runtime) ----------
__device__ __forceinline__ void load_edge(const void* ei, int flag, int e, int& s, int& d) {
    if (flag) {  // int64 data
        const long long* p = (const long long*)ei;
        s = (int)p[e];
        d = (int)p[e + N_EDGES];
    } else {     // int32 data
        const int* p = (const int*)ei;
        s = p[e];
        d = p[e + N_EDGES];
    }
}
__device__ __forceinline__ int load_dst(const void* ei, int flag, int e) {
    return flag ? (int)((const long long*)ei)[e + N_EDGES]
                : ((const int*)ei)[e + N_EDGES];
}

// flag=1 iff data is int64: odd int32 words (high halves) are all zero.
__global__ __launch_bounds__(256) void detect_kernel(const unsigned* ei, int* flagp) {
    __shared__ unsigned red[256];
    unsigned acc = 0;
    for (int i = threadIdx.x; i < 2048; i += 256) acc |= ei[2 * i + 1];
    red[threadIdx.x] = acc;
    __syncthreads();
    if (threadIdx.x == 0) {
        unsigned o = 0;
        for (int i = 0; i < 256; ++i) o |= red[i];
        *flagp = (o == 0) ? 1 : 0;
    }
}

// ---- pass A: per-block bucket histogram + LDS-aggregated bucket totals ----
// ghistT layout: [bucket][block]
__global__ __launch_bounds__(256) void hist_kernel(const void* ei, const int* flagp,
                                                   int* __restrict__ ghistT,
                                                   int* __restrict__ btotal) {
    __shared__ int h[NBUCK];
    const int flag = *flagp;
    const int t = threadIdx.x;
    if (t < NBUCK) h[t] = 0;
    __syncthreads();
    const int base = blockIdx.x * EPB;
    for (int i = t; i < EPB; i += 256)
        atomicAdd(&h[load_dst(ei, flag, base + i) >> 8], 1);
    __syncthreads();
    if (t < NBUCK) {
        ghistT[t * NBLK + blockIdx.x] = h[t];
        if (h[t]) atomicAdd(&btotal[t], h[t]);
    }
}

// ---- pass B1: exclusive scan of the 196 bucket totals (1 tiny block) ------
__global__ __launch_bounds__(256) void btot_kernel(const int* __restrict__ btotal,
                                                   int* __restrict__ bstart) {
    __shared__ int sm[256];
    const int t = threadIdx.x;
    int v = (t < NBUCK) ? btotal[t] : 0;
    sm[t] = v;
    __syncthreads();
    for (int off = 1; off < 256; off <<= 1) {
        int u = (t >= off) ? sm[t - off] : 0;
        __syncthreads();
        sm[t] += u;
        __syncthreads();
    }
    if (t < NBUCK) bstart[t] = sm[t] - v;
    if (t == 255) bstart[NBUCK] = sm[255];
}

// ---- pass B2: per-bucket scan over the 256 block counts -> goff[blk][b] ---
__global__ __launch_bounds__(256) void offs_kernel(const int* __restrict__ bstart,
                                                   const int* __restrict__ ghistT,
                                                   int* __restrict__ goff) {
    __shared__ int sm[256];
    const int b = blockIdx.x;
    const int t = threadIdx.x;
    int v = ghistT[b * NBLK + t];
    sm[t] = v;
    __syncthreads();
    for (int off = 1; off < 256; off <<= 1) {
        int u = (t >= off) ? sm[t - off] : 0;
        __syncthreads();
        sm[t] += u;
        __syncthreads();
    }
    goff[t * NBUCK + b] = bstart[b] + sm[t] - v;  // exclusive prefix
}

// ---- pass C: scatter into disjoint per-(block,bucket) ranges --------------
__global__ __launch_bounds__(256) void scatter_kernel(const void* ei, const int* flagp,
                                                      const int* __restrict__ goff,
                                                      unsigned* __restrict__ packed) {
    __shared__ int lcur[NBUCK];
    const int flag = *flagp;
    const int t = threadIdx.x;
    if (t < NBUCK) lcur[t] = goff[blockIdx.x * NBUCK + t];
    __syncthreads();
    const int base = blockIdx.x * EPB;
    for (int i = t; i < EPB; i += 256) {
        int s, d;
        load_edge(ei, flag, base + i, s, d);
        int b = d >> 8;
        int pos = atomicAdd(&lcur[b], 1);
        packed[pos] = (unsigned)s | ((unsigned)(d & 255) << 16);
    }
}

// ---- pass D: per-bucket LDS sort; also computes rowptr, dis ---------------
__global__ __launch_bounds__(256) void bucket_kernel(const int* __restrict__ bstart,
                                                     const unsigned* __restrict__ packed,
                                                     int* __restrict__ rowptr,
                                                     float* __restrict__ dis,
                                                     int* __restrict__ sortedsrc) {
    __shared__ int cnt[256];
    __shared__ int pref[256];
    __shared__ int lbuf[BCAP];
    const int b = blockIdx.x;
    const int nodebase = b << 8;
    const int rbase = bstart[b];
    const int bsize = bstart[b + 1] - rbase;
    const int t = threadIdx.x;
    const int nb = min(256, N_NODES - nodebase);

    cnt[t] = 0;
    __syncthreads();
    for (int i = t; i < bsize; i += 256)
        atomicAdd(&cnt[packed[rbase + i] >> 16], 1);
    __syncthreads();
    const int deg = cnt[t];
    pref[t] = deg;
    __syncthreads();
    for (int off = 1; off < 256; off <<= 1) {
        int u = (t >= off) ? pref[t - off] : 0;
        __syncthreads();
        pref[t] += u;
        __syncthreads();
    }
    const int excl = pref[t] - deg;
    if (t < nb) {
        rowptr[nodebase + t] = rbase + excl;
        dis[nodebase + t] = rsqrtf((float)deg + 1.0f);
    }
    if (b == NBUCK - 1 && t == 0) rowptr[N_NODES] = rbase + bsize;
    __syncthreads();
    cnt[t] = excl;  // reuse as cursor
    __syncthreads();
    if (bsize <= BCAP) {
        for (int i = t; i < bsize; i += 256) {
            unsigned p = packed[rbase + i];
            int pos = atomicAdd(&cnt[p >> 16], 1);
            lbuf[pos] = (int)(p & 0xFFFFu);
        }
        __syncthreads();
        for (int i = t; i < bsize; i += 256)
            sortedsrc[rbase + i] = lbuf[i];
    } else {
        // fallback: direct global scatter (pathological skew only)
        for (int i = t; i < bsize; i += 256) {
            unsigned p = packed[rbase + i];
            int pos = atomicAdd(&cnt[p >> 16], 1);
            sortedsrc[rbase + pos] = (int)(p & 0xFFFFu);
        }
    }
}

// --------------- GEMM1 (MFMA bf16): h1b = bf16(x @ W1) ---------------------
// block: 64 rows x 64 cols, K=128; 4 waves, each wave 16 rows x 64 cols.
__global__ __launch_bounds__(256) void gemm1_kernel(
        const float* __restrict__ x, const float* __restrict__ W1,
        unsigned short* __restrict__ h1b) {
    __shared__ unsigned short xa[64][136];  // x tile, bf16, +8 pad
    __shared__ unsigned short wb[64][136];  // W1 transposed [n][k], bf16
    const int t = threadIdx.x;
    const int w = t >> 6;
    const int l = t & 63;
    const int brow = blockIdx.x * 64;

    for (int f = t; f < 64 * 32; f += 256) {
        int r = f >> 5, c = (f & 31) << 2;
        int gr = brow + r;
        float4 v = (gr < N_NODES) ? *(const float4*)(x + gr * IN_CH + c)
                                  : make_float4(0.f, 0.f, 0.f, 0.f);
        xa[r][c + 0] = bf16rne(v.x); xa[r][c + 1] = bf16rne(v.y);
        xa[r][c + 2] = bf16rne(v.z); xa[r][c + 3] = bf16rne(v.w);
    }
    for (int f = t; f < 128 * 16; f += 256) {
        int k = f >> 4, n = (f & 15) << 2;
        float4 v = *(const float4*)(W1 + k * HID + n);
        wb[n + 0][k] = bf16rne(v.x); wb[n + 1][k] = bf16rne(v.y);
        wb[n + 2][k] = bf16rne(v.z); wb[n + 3][k] = bf16rne(v.w);
    }
    __syncthreads();

    const int fr = l & 15;
    const int fk = (l >> 4) << 3;
    f32x4 acc[4] = {{0.f,0.f,0.f,0.f},{0.f,0.f,0.f,0.f},{0.f,0.f,0.f,0.f},{0.f,0.f,0.f,0.f}};
#pragma unroll
    for (int kb = 0; kb < 4; ++kb) {
        const int k = kb * 32 + fk;
        bf16x8 a = *(const bf16x8*)&xa[w * 16 + fr][k];
#pragma unroll
        for (int n = 0; n < 4; ++n) {
            bf16x8 bfr = *(const bf16x8*)&wb[n * 16 + fr][k];
            acc[n] = __builtin_amdgcn_mfma_f32_16x16x32_bf16(a, bfr, acc[n], 0, 0, 0);
        }
    }
    const int rb = brow + w * 16 + ((l >> 4) << 2);
#pragma unroll
    for (int n = 0; n < 4; ++n) {
#pragma unroll
        for (int i = 0; i < 4; ++i) {
            int r = rb + i;
            if (r < N_NODES) h1b[r * HID + n * 16 + fr] = bf16rne(acc[n][i]);
        }
    }
}

// ---- agg1: wave per dst; 8 groups x 8 lanes, bf16x8 (16B) gathers ---------
// agg1b[d][c] = bf16(relu( sum_j h1[src_j][c]*norm_j + h1[d][c]*dd^2 + b1[c] ))
__global__ __launch_bounds__(256) void agg1_kernel(
        const int* __restrict__ rowptr, const int* __restrict__ sortedsrc,
        const float* __restrict__ dis, const unsigned short* __restrict__ h1b,
        const float* __restrict__ b1, unsigned short* __restrict__ agg1b) {
    const int l = threadIdx.x & 63;
    const int g = l >> 3;    // edge group 0-7
    const int cl = l & 7;    // 8 channels: 8cl..8cl+7
    const int d = blockIdx.x * 4 + (threadIdx.x >> 6);
    if (d >= N_NODES) return;
    const int beg = rowptr[d], end = rowptr[d + 1];
    const float dd = dis[d];
    float a0 = 0.f, a1 = 0.f, a2 = 0.f, a3 = 0.f;
    float a4 = 0.f, a5 = 0.f, a6 = 0.f, a7 = 0.f;
    for (int j = beg + g; j < end; j += 8) {
        int s = sortedsrc[j];
        float n = dis[s] * dd;
        bf16x8 h = *(const bf16x8*)(h1b + s * HID + 8 * cl);
        a0 += bf16f((unsigned short)h[0]) * n; a1 += bf16f((unsigned short)h[1]) * n;
        a2 += bf16f((unsigned short)h[2]) * n; a3 += bf16f((unsigned short)h[3]) * n;
        a4 += bf16f((unsigned short)h[4]) * n; a5 += bf16f((unsigned short)h[5]) * n;
        a6 += bf16f((unsigned short)h[6]) * n; a7 += bf16f((unsigned short)h[7]) * n;
    }
    // reduce across the 8 edge-groups (lane bits 3,4,5)
#pragma unroll
    for (int st = 8; st <= 32; st <<= 1) {
        a0 += __shfl_xor(a0, st, 64); a1 += __shfl_xor(a1, st, 64);
        a2 += __shfl_xor(a2, st, 64); a3 += __shfl_xor(a3, st, 64);
        a4 += __shfl_xor(a4, st, 64); a5 += __shfl_xor(a5, st, 64);
        a6 += __shfl_xor(a6, st, 64); a7 += __shfl_xor(a7, st, 64);
    }
    if (g == 0) {
        bf16x8 hs = *(const bf16x8*)(h1b + d * HID + 8 * cl);
        float4 bv0 = *(const float4*)(b1 + 8 * cl);
        float4 bv1 = *(const float4*)(b1 + 8 * cl + 4);
        float d2 = dd * dd;
        u16x8 o;
        o[0] = bf16rne(fmaxf(a0 + bf16f((unsigned short)hs[0]) * d2 + bv0.x, 0.f));
        o[1] = bf16rne(fmaxf(a1 + bf16f((unsigned short)hs[1]) * d2 + bv0.y, 0.f));
        o[2] = bf16rne(fmaxf(a2 + bf16f((unsigned short)hs[2]) * d2 + bv0.z, 0.f));
        o[3] = bf16rne(fmaxf(a3 + bf16f((unsigned short)hs[3]) * d2 + bv0.w, 0.f));
        o[4] = bf16rne(fmaxf(a4 + bf16f((unsigned short)hs[4]) * d2 + bv1.x, 0.f));
        o[5] = bf16rne(fmaxf(a5 + bf16f((unsigned short)hs[5]) * d2 + bv1.y, 0.f));
        o[6] = bf16rne(fmaxf(a6 + bf16f((unsigned short)hs[6]) * d2 + bv1.z, 0.f));
        o[7] = bf16rne(fmaxf(a7 + bf16f((unsigned short)hs[7]) * d2 + bv1.w, 0.f));
        *(u16x8*)(agg1b + d * HID + 8 * cl) = o;
    }
}

// --------------- GEMM2 (MFMA bf16): h2b = bf16(agg1b @ W2) -----------------
// block: 64 rows x 32 cols, K=64; 4 waves, each wave 16 rows x 32 cols.
__global__ __launch_bounds__(256) void gemm2_kernel(
        const unsigned short* __restrict__ agg1b, const float* __restrict__ W2,
        unsigned short* __restrict__ h2b) {
    __shared__ unsigned short xa[64][72];   // agg1b tile (64x64), +8 pad
    __shared__ unsigned short wb[32][72];   // W2 transposed [n][k]
    const int t = threadIdx.x;
    const int w = t >> 6;
    const int l = t & 63;
    const int brow = blockIdx.x * 64;

    for (int f = t; f < 64 * 16; f += 256) {
        int r = f >> 4, c = (f & 15) << 2;
        int gr = brow + r;
        ushort4 v = make_ushort4(0, 0, 0, 0);
        if (gr < N_NODES) v = *(const ushort4*)(agg1b + gr * HID + c);
        *(ushort4*)&xa[r][c] = v;
    }
    for (int f = t; f < 64 * 8; f += 256) {
        int k = f >> 3, n = (f & 7) << 2;
        float4 v = *(const float4*)(W2 + k * OUT_CH + n);
        wb[n + 0][k] = bf16rne(v.x); wb[n + 1][k] = bf16rne(v.y);
        wb[n + 2][k] = bf16rne(v.z); wb[n + 3][k] = bf16rne(v.w);
    }
    __syncthreads();

    const int fr = l & 15;
    const int fk = (l >> 4) << 3;
    f32x4 acc[2] = {{0.f,0.f,0.f,0.f},{0.f,0.f,0.f,0.f}};
#pragma unroll
    for (int kb = 0; kb < 2; ++kb) {
        const int k = kb * 32 + fk;
        bf16x8 a = *(const bf16x8*)&xa[w * 16 + fr][k];
#pragma unroll
        for (int n = 0; n < 2; ++n) {
            bf16x8 bfr = *(const bf16x8*)&wb[n * 16 + fr][k];
            acc[n] = __builtin_amdgcn_mfma_f32_16x16x32_bf16(a, bfr, acc[n], 0, 0, 0);
        }
    }
    const int rb = brow + w * 16 + ((l >> 4) << 2);
#pragma unroll
    for (int n = 0; n < 2; ++n) {
#pragma unroll
        for (int i = 0; i < 4; ++i) {
            int r = rb + i;
            if (r < N_NODES) h2b[r * OUT_CH + n * 16 + fr] = bf16rne(acc[n][i]);
        }
    }
}

// ---- agg2: wave per dst; 16 groups x 4 lanes, bf16x8 (16B) gathers --------
// out[d][c] = sum_j h2[src_j][c]*norm_j + h2[d][c]*dd^2 + b2[c]
__global__ __launch_bounds__(256) void agg2_kernel(
        const int* __restrict__ rowptr, const int* __restrict__ sortedsrc,
        const float* __restrict__ dis, const unsigned short* __restrict__ h2b,
        const float* __restrict__ b2, float* __restrict__ out) {
    const int l = threadIdx.x & 63;
    const int g = l >> 2;    // edge group 0-15
    const int cl = l & 3;    // 8 channels: 8cl..8cl+7
    const int d = blockIdx.x * 4 + (threadIdx.x >> 6);
    if (d >= N_NODES) return;
    const int beg = rowptr[d], end = rowptr[d + 1];
    const float dd = dis[d];
    float a0 = 0.f, a1 = 0.f, a2 = 0.f, a3 = 0.f;
    float a4 = 0.f, a5 = 0.f, a6 = 0.f, a7 = 0.f;
    for (int j = beg + g; j < end; j += 16) {
        int s = sortedsrc[j];
        float n = dis[s] * dd;
        bf16x8 h = *(const bf16x8*)(h2b + s * OUT_CH + 8 * cl);
        a0 += bf16f((unsigned short)h[0]) * n; a1 += bf16f((unsigned short)h[1]) * n;
        a2 += bf16f((unsigned short)h[2]) * n; a3 += bf16f((unsigned short)h[3]) * n;
        a4 += bf16f((unsigned short)h[4]) * n; a5 += bf16f((unsigned short)h[5]) * n;
        a6 += bf16f((unsigned short)h[6]) * n; a7 += bf16f((unsigned short)h[7]) * n;
    }
    // reduce across the 16 edge-groups (lane bits 2,3,4,5)
#pragma unroll
    for (int st = 4; st <= 32; st <<= 1) {
        a0 += __shfl_xor(a0, st, 64); a1 += __shfl_xor(a1, st, 64);
        a2 += __shfl_xor(a2, st, 64); a3 += __shfl_xor(a3, st, 64);
        a4 += __shfl_xor(a4, st, 64); a5 += __shfl_xor(a5, st, 64);
        a6 += __shfl_xor(a6, st, 64); a7 += __shfl_xor(a7, st, 64);
    }
    if (g == 0) {
        bf16x8 hs = *(const bf16x8*)(h2b + d * OUT_CH + 8 * cl);
        float4 bv0 = *(const float4*)(b2 + 8 * cl);
        float4 bv1 = *(const float4*)(b2 + 8 * cl + 4);
        float d2 = dd * dd;
        float4 o0, o1;
        o0.x = a0 + bf16f((unsigned short)hs[0]) * d2 + bv0.x;
        o0.y = a1 + bf16f((unsigned short)hs[1]) * d2 + bv0.y;
        o0.z = a2 + bf16f((unsigned short)hs[2]) * d2 + bv0.z;
        o0.w = a3 + bf16f((unsigned short)hs[3]) * d2 + bv0.w;
        o1.x = a4 + bf16f((unsigned short)hs[4]) * d2 + bv1.x;
        o1.y = a5 + bf16f((unsigned short)hs[5]) * d2 + bv1.y;
        o1.z = a6 + bf16f((unsigned short)hs[6]) * d2 + bv1.z;
        o1.w = a7 + bf16f((unsigned short)hs[7]) * d2 + bv1.w;
        *(float4*)(out + d * OUT_CH + 8 * cl) = o0;
        *(float4*)(out + d * OUT_CH + 8 * cl + 4) = o1;
    }
}

extern "C" void kernel_launch(void* const* d_in, const int* in_sizes, int n_in,
                              void* d_out, int out_size, void* d_ws, size_t ws_size,
                              hipStream_t stream) {
    const float* x  = (const float*)d_in[0];
    const float* W1 = (const float*)d_in[1];
    const float* b1 = (const float*)d_in[2];
    const float* W2 = (const float*)d_in[3];
    const float* b2 = (const float*)d_in[4];
    const void*  ei = d_in[5];
    float* out = (float*)d_out;

    char* wp = (char*)d_ws;
    auto alloc = [&](size_t n) { char* p = wp; wp += (n + 511) & ~(size_t)511; return p; };
    int*   flagp  = (int*)alloc(4);
    int*   btotal = (int*)alloc(NBUCK * 4);
    int*   bstart = (int*)alloc((NBUCK + 1) * 4);
    int*   ghistT = (int*)alloc((size_t)NBUCK * NBLK * 4);   // 200 KB
    int*   goff   = (int*)alloc((size_t)NBLK * NBUCK * 4);   // 200 KB
    int*   rowptr = (int*)alloc((size_t)(N_NODES + 1) * 4);  // 200 KB
    float* dis    = (float*)alloc((size_t)N_NODES * 4);      // 200 KB
    int*   sortedsrc = (int*)alloc((size_t)N_EDGES * 4);     // 3.2 MB
    unsigned* packed = (unsigned*)alloc((size_t)N_EDGES * 4);             // 3.2 MB
    unsigned short* h1b = (unsigned short*)alloc((size_t)N_NODES * HID * 2);    // 6.4 MB
    unsigned short* agg1b = (unsigned short*)alloc((size_t)N_NODES * HID * 2);  // 6.4 MB
    unsigned short* h2b = (unsigned short*)alloc((size_t)N_NODES * OUT_CH * 2); // 3.2 MB

    hipMemsetAsync(btotal, 0, NBUCK * sizeof(int), stream);
    detect_kernel<<<1, 256, 0, stream>>>((const unsigned*)ei, flagp);
    hist_kernel<<<NBLK, 256, 0, stream>>>(ei, flagp, ghistT, btotal);
    btot_kernel<<<1, 256, 0, stream>>>(btotal, bstart);
    offs_kernel<<<NBUCK, 256, 0, stream>>>(bstart, ghistT, goff);
    scatter_kernel<<<NBLK, 256, 0, stream>>>(ei, flagp, goff, packed);
    bucket_kernel<<<NBUCK, 256, 0, stream>>>(bstart, packed, rowptr, dis, sortedsrc);

    gemm1_kernel<<<(N_NODES + 63) / 64, 256, 0, stream>>>(x, W1, h1b);

    agg1_kernel<<<(N_NODES + 3) / 4, 256, 0, stream>>>(rowptr, sortedsrc, dis, h1b, b1, agg1b);

    gemm2_kernel<<<(N_NODES + 63) / 64, 256, 0, stream>>>(agg1b, W2, h2b);

    agg2_kernel<<<(N_NODES + 3) / 4, 256, 0, stream>>>(rowptr, sortedsrc, dis, h2b, b2, out);
}